// Round 6
// baseline (842.269 us; speedup 1.0000x reference)
//
#include <hip/hip_runtime.h>
#include <hip/hip_cooperative_groups.h>
#include <math.h>

namespace cg = cooperative_groups;

#define N 1024
#define IN_DIM 16
#define HID 64
#define MAXD 64
#define GRID 512

__device__ __forceinline__ float sigmoidf_(float x) {
    return 1.0f / (1.0f + __expf(-x));
}
// fast tanh via exp; ~1e-6 rel error, far below 1e-2 threshold
__device__ __forceinline__ float ftanh_(float x) {
    float e = __expf(2.0f * x);
    return 1.0f - 2.0f / (e + 1.0f);
}

__global__ void __launch_bounds__(256, 4) fused_kernel(
    const float* __restrict__ A, const float* __restrict__ E,
    const float* __restrict__ X,
    const float* __restrict__ W_enc, const float* __restrict__ b_enc,
    const float* __restrict__ W_msg, const float* __restrict__ b_msg,
    const float* __restrict__ W_ih, const float* __restrict__ W_hh,
    const float* __restrict__ b_ih, const float* __restrict__ b_hh,
    const float* __restrict__ W_r1, const float* __restrict__ b_r1,
    const float* __restrict__ W_r2, const float* __restrict__ b_r2,
    const int* __restrict__ src, const int* __restrict__ tgt,
    float* __restrict__ ws, float* __restrict__ out)
{
    cg::grid_group grid = cg::this_grid();

    // workspace layout (floats)
    float* h0    = ws;                       // N*HID
    float* h1    = h0 + N * HID;             // N*HID
    float* p0    = h1 + N * HID;             // N*HID
    float* p1    = p0 + N * HID;             // N*HID
    float* deg   = p1 + N * HID;             // N
    float* ev    = deg + N;                  // N*MAXD
    int*   nbr   = (int*)(ev + N * MAXD);    // N*MAXD ints
    float* WihT  = (float*)(nbr + N * MAXD); // [64][192]
    float* WhhT  = WihT + 64 * 192;          // [64][192]
    float* WmsgT = WhhT + 64 * 192;          // [64][64]
    float* Wr1T  = WmsgT + 64 * 64;          // [128][64]

    int bid = blockIdx.x;
    int tid = threadIdx.x;
    int wave = tid >> 6;
    int lane = tid & 63;

    __shared__ float sm[4][2][HID];          // step phase: [0]=msgs/hnew, [1]=h_u
    __shared__ unsigned long long balls[16]; // CSR phase
    __shared__ int base[16];

    // ================= phase 0: CSR (2 rows/block) + encoder + transposes ======
    for (int rr = 0; rr < 2; ++rr) {
        int u = bid * 2 + rr;
        float evr[4];
        bool has[4];
#pragma unroll
        for (int ci = 0; ci < 4; ++ci) {
            int chunk = wave * 4 + ci;
            int v = chunk * 64 + lane;
            float a = A[u * N + v];
            bool hs = (a > 0.0f);
            has[ci] = hs;
            evr[ci] = E[u * N + v];
            unsigned long long b = __ballot(hs);
            if (lane == 0) balls[chunk] = b;
        }
        __syncthreads();
        if (tid == 0) {
            int s = 0;
#pragma unroll
            for (int c = 0; c < 16; ++c) {
                base[c] = s;
                s += __popcll(balls[c]);
            }
            deg[u] = (float)s;
        }
        __syncthreads();
#pragma unroll
        for (int ci = 0; ci < 4; ++ci) {
            int chunk = wave * 4 + ci;
            if (has[ci]) {
                unsigned long long b = balls[chunk];
                int slot = base[chunk] + __popcll(b & ((1ull << lane) - 1ull));
                if (slot < MAXD) {
                    nbr[u * MAXD + slot] = chunk * 64 + lane;
                    ev[u * MAXD + slot] = evr[ci];
                }
            }
        }
        __syncthreads();   // balls/base reused next row
    }

    if (wave < 2) {
        // ---- encoder + proj0 for node u = bid*2 + wave (in-wave via shfl) ----
        int u = bid * 2 + wave;
        float acc = b_enc[lane];
#pragma unroll
        for (int k = 0; k < IN_DIM; ++k)
            acc += X[u * IN_DIM + k] * W_enc[lane * IN_DIM + k];
        float hv = tanhf(acc);
        h0[u * HID + lane] = hv;
        float pacc = b_msg[lane];
#pragma unroll
        for (int k = 0; k < HID; ++k) {
            float hk = __shfl(hv, k);
            pacc += hk * W_msg[lane * (HID + 1) + k];
        }
        p0[u * HID + lane] = pacc;
    } else if (bid < 288) {
        // ---- weight transposes: 128 threads x 288 blocks = 36864 elements ----
        int t = bid * 128 + (tid - 128);
        if (t < 12288) {                       // WihT[k*192+r] = W_ih[r*64+k]
            int r = t >> 6, k = t & 63;
            WihT[k * 192 + r] = W_ih[t];
        } else if (t < 24576) {                // WhhT
            int t0 = t - 12288;
            int r = t0 >> 6, k = t0 & 63;
            WhhT[k * 192 + r] = W_hh[t0];
        } else if (t < 28672) {                // WmsgT[k*64+j] = W_msg[j*65+k]
            int t0 = t - 24576;
            int j = t0 >> 6, k = t0 & 63;
            WmsgT[k * 64 + j] = W_msg[j * (HID + 1) + k];
        } else {                               // Wr1T[k*64+j] = W_r1[j*128+k]
            int t0 = t - 28672;
            int j = t0 >> 7, k = t0 & 127;
            Wr1T[k * 64 + j] = W_r1[t0];
        }
    }

    grid.sync();

    // ================= phases 1-3: message-passing + GRU steps ==================
    float* hc = h0; float* hn = h1;
    float* pc = p0; float* pn = p1;
    for (int s = 0; s < 3; ++s) {
        if (bid < 256) {
            int u = bid * 4 + wave;          // wave = node slot, lane = hidden idx

            float we = W_msg[lane * (HID + 1) + HID];
            float d = deg[u];
            int dn = (int)d;
            float sum = 0.0f;
            int i = 0;
            for (; i + 4 <= dn; i += 4) {
                int4 nb = *(const int4*)&nbr[u * MAXD + i];
                float4 e4 = *(const float4*)&ev[u * MAXD + i];
                float q0 = pc[nb.x * HID + lane];
                float q1 = pc[nb.y * HID + lane];
                float q2 = pc[nb.z * HID + lane];
                float q3 = pc[nb.w * HID + lane];
                sum += ftanh_(q0 + e4.x * we);
                sum += ftanh_(q1 + e4.y * we);
                sum += ftanh_(q2 + e4.z * we);
                sum += ftanh_(q3 + e4.w * we);
            }
            for (; i < dn; ++i) {
                int v = nbr[u * MAXD + i];
                sum += ftanh_(pc[v * HID + lane] + ev[u * MAXD + i] * we);
            }
            float msg = (dn > 0) ? (sum / d) : 0.0f;
            float hu = hc[u * HID + lane];

            sm[wave][0][lane] = msg;
            sm[wave][1][lane] = hu;
            __syncthreads();

            // GRU: lane j = output j; weight reads coalesced via transposed mats
            float accR  = b_ih[lane]       + b_hh[lane];
            float accZ  = b_ih[64 + lane]  + b_hh[64 + lane];
            float accNi = b_ih[128 + lane];
            float accNh = b_hh[128 + lane];
            const float4* m4 = (const float4*)sm[wave][0];
            const float4* h4 = (const float4*)sm[wave][1];
#pragma unroll
            for (int k4 = 0; k4 < 16; ++k4) {
                float4 mv = m4[k4];
                float4 hv = h4[k4];
#pragma unroll
                for (int t = 0; t < 4; ++t) {
                    int k = k4 * 4 + t;
                    const float* wi = &WihT[k * 192];
                    const float* wh = &WhhT[k * 192];
                    float mk = (&mv.x)[t];
                    float hk = (&hv.x)[t];
                    accR  += mk * wi[lane]       + hk * wh[lane];
                    accZ  += mk * wi[64 + lane]  + hk * wh[64 + lane];
                    accNi += mk * wi[128 + lane];
                    accNh += hk * wh[128 + lane];
                }
            }
            float r = sigmoidf_(accR);
            float z = sigmoidf_(accZ);
            float n = ftanh_(accNi + r * accNh);
            float hnew = (1.0f - z) * n + z * hu;
            hn[u * HID + lane] = hnew;

            if (s < 2) {
                __syncthreads();             // all waves done reading sm
                sm[wave][0][lane] = hnew;
                __syncthreads();
                float pacc = b_msg[lane];
                const float4* n4 = (const float4*)sm[wave][0];
#pragma unroll
                for (int k4 = 0; k4 < 16; ++k4) {
                    float4 hh = n4[k4];
#pragma unroll
                    for (int t = 0; t < 4; ++t) {
                        int k = k4 * 4 + t;
                        pacc += (&hh.x)[t] * WmsgT[k * 64 + lane];
                    }
                }
                pn[u * HID + lane] = pacc;
            }
        }
        grid.sync();
        float* tm = hc; hc = hn; hn = tm;
        tm = pc; pc = pn; pn = tm;
    }

    // ================= phase 4: readout (block 0, wave 0) =======================
    if (bid == 0 && tid < 64) {
        int sI = src[0];
        int tI = tgt[0];
        float acc = b_r1[lane];
#pragma unroll 8
        for (int k = 0; k < HID; ++k)
            acc += hc[sI * HID + k] * Wr1T[k * 64 + lane];
#pragma unroll 8
        for (int k = 0; k < HID; ++k)
            acc += hc[tI * HID + k] * Wr1T[(HID + k) * 64 + lane];
        float hid = fmaxf(acc, 0.0f);
        float p = hid * W_r2[lane];
#pragma unroll
        for (int off = 32; off > 0; off >>= 1)
            p += __shfl_down(p, off);
        if (lane == 0) out[0] = sigmoidf_(p + b_r2[0]);
    }
}

extern "C" void kernel_launch(void* const* d_in, const int* in_sizes, int n_in,
                              void* d_out, int out_size, void* d_ws, size_t ws_size,
                              hipStream_t stream) {
    const float* A     = (const float*)d_in[0];
    const float* E     = (const float*)d_in[1];
    const float* X     = (const float*)d_in[2];
    const float* W_enc = (const float*)d_in[3];
    const float* b_enc = (const float*)d_in[4];
    const float* W_msg = (const float*)d_in[5];
    const float* b_msg = (const float*)d_in[6];
    const float* W_ih  = (const float*)d_in[7];
    const float* W_hh  = (const float*)d_in[8];
    const float* b_ih  = (const float*)d_in[9];
    const float* b_hh  = (const float*)d_in[10];
    const float* W_r1  = (const float*)d_in[11];
    const float* b_r1  = (const float*)d_in[12];
    const float* W_r2  = (const float*)d_in[13];
    const float* b_r2  = (const float*)d_in[14];
    const int*   src   = (const int*)d_in[15];
    const int*   tgt   = (const int*)d_in[16];
    // steps fixed at 3 in the reference.

    float* ws  = (float*)d_ws;
    float* out = (float*)d_out;

    void* args[] = {
        (void*)&A, (void*)&E, (void*)&X,
        (void*)&W_enc, (void*)&b_enc, (void*)&W_msg, (void*)&b_msg,
        (void*)&W_ih, (void*)&W_hh, (void*)&b_ih, (void*)&b_hh,
        (void*)&W_r1, (void*)&b_r1, (void*)&W_r2, (void*)&b_r2,
        (void*)&src, (void*)&tgt, (void*)&ws, (void*)&out
    };
    hipLaunchCooperativeKernel((const void*)fused_kernel, dim3(GRID), dim3(256),
                               args, 0, stream);
}

// Round 7
// 400.008 us; speedup vs baseline: 2.1056x; 2.1056x over previous
//
#include <hip/hip_runtime.h>
#include <math.h>

#define N 1024
#define IN_DIM 16
#define HID 64
#define MAXD 64
#define SBLK 256   // blocks in steps kernel

__device__ __forceinline__ float sigmoidf_(float x) {
    return 1.0f / (1.0f + __expf(-x));
}
// fast tanh via exp; ~1e-6 rel error, far below 1e-2 threshold
__device__ __forceinline__ float ftanh_(float x) {
    float e = __expf(2.0f * x);
    return 1.0f - 2.0f / (e + 1.0f);
}

// ---- fused init (round-5 proven):
//   blocks [0,256)    : encoder + proj0 (4 nodes/block)
//   blocks [256,1280) : CSR build (1 block/row)
//   blocks [1280,1424): weight transposes; block 1423 also zeroes barrier state
__global__ void init_kernel(const float* __restrict__ X,
                            const float* __restrict__ W_enc,
                            const float* __restrict__ b_enc,
                            const float* __restrict__ W_msg,
                            const float* __restrict__ b_msg,
                            const float* __restrict__ W_ih,
                            const float* __restrict__ W_hh,
                            const float* __restrict__ W_r1,
                            const float* __restrict__ A,
                            const float* __restrict__ E,
                            float* __restrict__ h,
                            float* __restrict__ proj,
                            int* __restrict__ nbr,
                            float* __restrict__ ev,
                            float* __restrict__ deg,
                            float* __restrict__ WihT,
                            float* __restrict__ WhhT,
                            float* __restrict__ WmsgT,
                            float* __restrict__ Wr1T,
                            unsigned* __restrict__ bar) {
    int bid = blockIdx.x;
    int tid = threadIdx.x;
    int wave = tid >> 6;
    int lane = tid & 63;

    if (bid < 256) {
        // ---- encoder + proj0 ----
        int u = bid * 4 + wave;
        __shared__ float sh[4][HID];
        float acc = b_enc[lane];
#pragma unroll
        for (int k = 0; k < IN_DIM; ++k)
            acc += X[u * IN_DIM + k] * W_enc[lane * IN_DIM + k];
        float hv = tanhf(acc);
        h[u * HID + lane] = hv;
        sh[wave][lane] = hv;
        __syncthreads();
        float pacc = b_msg[lane];
        const float4* h4 = (const float4*)sh[wave];
#pragma unroll
        for (int k4 = 0; k4 < HID / 4; ++k4) {
            float4 hh = h4[k4];
            const float* w = &W_msg[lane * (HID + 1) + k4 * 4];
            pacc += hh.x * w[0] + hh.y * w[1] + hh.z * w[2] + hh.w * w[3];
        }
        proj[u * HID + lane] = pacc;
    } else if (bid < 1280) {
        // ---- CSR build: one 256-thread block per row u ----
        int u = bid - 256;
        __shared__ unsigned long long balls[16];
        __shared__ int base[16];
        float evr[4];
        bool has[4];
#pragma unroll
        for (int ci = 0; ci < 4; ++ci) {
            int chunk = wave * 4 + ci;
            int v = chunk * 64 + lane;
            float a = A[u * N + v];
            bool hs = (a > 0.0f);
            has[ci] = hs;
            evr[ci] = E[u * N + v];
            unsigned long long b = __ballot(hs);
            if (lane == 0) balls[chunk] = b;
        }
        __syncthreads();
        if (tid == 0) {
            int s = 0;
#pragma unroll
            for (int c = 0; c < 16; ++c) {
                base[c] = s;
                s += __popcll(balls[c]);
            }
            deg[u] = (float)s;
        }
        __syncthreads();
#pragma unroll
        for (int ci = 0; ci < 4; ++ci) {
            int chunk = wave * 4 + ci;
            if (has[ci]) {
                unsigned long long b = balls[chunk];
                int slot = base[chunk] + __popcll(b & ((1ull << lane) - 1ull));
                if (slot < MAXD) {
                    nbr[u * MAXD + slot] = chunk * 64 + lane;
                    ev[u * MAXD + slot] = evr[ci];
                }
            }
        }
    } else {
        // ---- weight transposes: flat element id over 36864 ----
        int t = (bid - 1280) * 256 + tid;
        if (t < 12288) {                       // WihT[k*192+r] = W_ih[r*64+k]
            int r = t >> 6, k = t & 63;
            WihT[k * 192 + r] = W_ih[t];
        } else if (t < 24576) {                // WhhT
            int t0 = t - 12288;
            int r = t0 >> 6, k = t0 & 63;
            WhhT[k * 192 + r] = W_hh[t0];
        } else if (t < 28672) {                // WmsgT[k*64+j] = W_msg[j*65+k]
            int t0 = t - 24576;
            int j = t0 >> 6, k = t0 & 63;
            WmsgT[k * 64 + j] = W_msg[j * (HID + 1) + k];
        } else {                               // Wr1T[k*64+j] = W_r1[j*128+k]
            int t0 = t - 28672;
            int j = t0 >> 7, k = t0 & 127;
            Wr1T[k * 64 + j] = W_r1[t0];
        }
        if (bid == 1423 && tid == 0) {         // reset barrier state every launch
            bar[0] = 0u;                       // arrival counter
            bar[1] = 0u;                       // generation
        }
    }
}

// ---- lightweight grid barrier: thread 0 only; relaxed polling + bounded spin ----
__device__ __forceinline__ void grid_barrier(unsigned* bar) {
    __syncthreads();
    if (threadIdx.x == 0) {
        __threadfence();   // release: make this block's writes device-visible
        unsigned g = __hip_atomic_load(&bar[1], __ATOMIC_RELAXED,
                                       __HIP_MEMORY_SCOPE_AGENT);
        unsigned old = __hip_atomic_fetch_add(&bar[0], 1u, __ATOMIC_ACQ_REL,
                                              __HIP_MEMORY_SCOPE_AGENT);
        if (old == SBLK - 1) {
            __hip_atomic_store(&bar[0], 0u, __ATOMIC_RELAXED,
                               __HIP_MEMORY_SCOPE_AGENT);
            __hip_atomic_store(&bar[1], g + 1u, __ATOMIC_RELEASE,
                               __HIP_MEMORY_SCOPE_AGENT);
        } else {
            int spins = 0;
            while (__hip_atomic_load(&bar[1], __ATOMIC_RELAXED,
                                     __HIP_MEMORY_SCOPE_AGENT) == g) {
                __builtin_amdgcn_s_sleep(2);
                if (++spins > (1 << 22)) break;   // safety: no infinite hang
            }
        }
        __threadfence();   // acquire: invalidate caches, see other blocks' writes
    }
    __syncthreads();
}

// ---- steps kernel: 3 x (msg-gather + GRU + proj) + readout, 1 barrier/step ----
__global__ void __launch_bounds__(256, 4) steps_kernel(
    const float* __restrict__ W_msg, const float* __restrict__ b_msg,
    const int* __restrict__ nbr, const float* __restrict__ ev,
    const float* __restrict__ deg,
    const float* __restrict__ WihT, const float* __restrict__ WhhT,
    const float* __restrict__ WmsgT,
    const float* __restrict__ b_ih, const float* __restrict__ b_hh,
    const float* __restrict__ Wr1T, const float* __restrict__ b_r1,
    const float* __restrict__ W_r2, const float* __restrict__ b_r2,
    const int* __restrict__ src, const int* __restrict__ tgt,
    float* __restrict__ h0, float* __restrict__ h1,
    float* __restrict__ p0, float* __restrict__ p1,
    unsigned* __restrict__ bar, float* __restrict__ out)
{
    int tid = threadIdx.x;
    int wave = tid >> 6;     // node slot within block
    int lane = tid & 63;     // hidden index
    int u = blockIdx.x * 4 + wave;

    __shared__ float sm[4][2][HID];
    __shared__ int   snbr[4][MAXD];
    __shared__ float sev[4][MAXD];

    // hoist this wave's CSR row into LDS (survives barrier cache invalidates)
    snbr[wave][lane] = nbr[u * MAXD + lane];
    sev[wave][lane]  = ev[u * MAXD + lane];
    float we = W_msg[lane * (HID + 1) + HID];
    float d = deg[u];
    int dn = (int)d;
    __syncthreads();

    float* hc = h0; float* hn = h1;
    float* pc = p0; float* pn = p1;

    for (int s = 0; s < 3; ++s) {
        // ---- message gather ----
        float sum = 0.0f;
        int i = 0;
        for (; i + 4 <= dn; i += 4) {
            int v0 = snbr[wave][i],     v1 = snbr[wave][i + 1];
            int v2 = snbr[wave][i + 2], v3 = snbr[wave][i + 3];
            float q0 = pc[v0 * HID + lane];
            float q1 = pc[v1 * HID + lane];
            float q2 = pc[v2 * HID + lane];
            float q3 = pc[v3 * HID + lane];
            sum += ftanh_(q0 + sev[wave][i]     * we);
            sum += ftanh_(q1 + sev[wave][i + 1] * we);
            sum += ftanh_(q2 + sev[wave][i + 2] * we);
            sum += ftanh_(q3 + sev[wave][i + 3] * we);
        }
        for (; i < dn; ++i)
            sum += ftanh_(pc[snbr[wave][i] * HID + lane] + sev[wave][i] * we);
        float msg = (dn > 0) ? (sum / d) : 0.0f;
        float hu = hc[u * HID + lane];

        sm[wave][0][lane] = msg;
        sm[wave][1][lane] = hu;
        __syncthreads();

        // ---- GRU: lane j = output j; weights coalesced via transposed mats ----
        float accR  = b_ih[lane]       + b_hh[lane];
        float accZ  = b_ih[64 + lane]  + b_hh[64 + lane];
        float accNi = b_ih[128 + lane];
        float accNh = b_hh[128 + lane];
        const float4* m4 = (const float4*)sm[wave][0];
        const float4* h4 = (const float4*)sm[wave][1];
#pragma unroll
        for (int k4 = 0; k4 < 16; ++k4) {
            float4 mv = m4[k4];
            float4 hv = h4[k4];
#pragma unroll
            for (int t = 0; t < 4; ++t) {
                int k = k4 * 4 + t;
                const float* wi = &WihT[k * 192];
                const float* wh = &WhhT[k * 192];
                float mk = (&mv.x)[t];
                float hk = (&hv.x)[t];
                accR  += mk * wi[lane]       + hk * wh[lane];
                accZ  += mk * wi[64 + lane]  + hk * wh[64 + lane];
                accNi += mk * wi[128 + lane];
                accNh += hk * wh[128 + lane];
            }
        }
        float r = sigmoidf_(accR);
        float z = sigmoidf_(accZ);
        float n = ftanh_(accNi + r * accNh);
        float hnew = (1.0f - z) * n + z * hu;
        hn[u * HID + lane] = hnew;

        if (s < 2) {
            __syncthreads();             // all waves done reading sm
            sm[wave][0][lane] = hnew;
            __syncthreads();
            float pacc = b_msg[lane];
            const float4* n4 = (const float4*)sm[wave][0];
#pragma unroll
            for (int k4 = 0; k4 < 16; ++k4) {
                float4 hh = n4[k4];
#pragma unroll
                for (int t = 0; t < 4; ++t) {
                    int k = k4 * 4 + t;
                    pacc += (&hh.x)[t] * WmsgT[k * 64 + lane];
                }
            }
            pn[u * HID + lane] = pacc;
        } else {
            __syncthreads();
        }

        grid_barrier(bar);               // step boundary (grid-wide dependency)

        float* tm = hc; hc = hn; hn = tm;
        tm = pc; pc = pn; pn = tm;
    }

    // ---- readout: block 0, wave 0 ----
    if (blockIdx.x == 0 && tid < 64) {
        int sI = src[0];
        int tI = tgt[0];
        float acc = b_r1[lane];
#pragma unroll 8
        for (int k = 0; k < HID; ++k)
            acc += hc[sI * HID + k] * Wr1T[k * 64 + lane];
#pragma unroll 8
        for (int k = 0; k < HID; ++k)
            acc += hc[tI * HID + k] * Wr1T[(HID + k) * 64 + lane];
        float hid = fmaxf(acc, 0.0f);
        float p = hid * W_r2[lane];
#pragma unroll
        for (int off = 32; off > 0; off >>= 1)
            p += __shfl_down(p, off);
        if (lane == 0) out[0] = sigmoidf_(p + b_r2[0]);
    }
}

extern "C" void kernel_launch(void* const* d_in, const int* in_sizes, int n_in,
                              void* d_out, int out_size, void* d_ws, size_t ws_size,
                              hipStream_t stream) {
    const float* A     = (const float*)d_in[0];
    const float* E     = (const float*)d_in[1];
    const float* X     = (const float*)d_in[2];
    const float* W_enc = (const float*)d_in[3];
    const float* b_enc = (const float*)d_in[4];
    const float* W_msg = (const float*)d_in[5];
    const float* b_msg = (const float*)d_in[6];
    const float* W_ih  = (const float*)d_in[7];
    const float* W_hh  = (const float*)d_in[8];
    const float* b_ih  = (const float*)d_in[9];
    const float* b_hh  = (const float*)d_in[10];
    const float* W_r1  = (const float*)d_in[11];
    const float* b_r1  = (const float*)d_in[12];
    const float* W_r2  = (const float*)d_in[13];
    const float* b_r2  = (const float*)d_in[14];
    const int*   src   = (const int*)d_in[15];
    const int*   tgt   = (const int*)d_in[16];
    // steps fixed at 3 in the reference.

    // workspace layout (floats)
    float* ws    = (float*)d_ws;
    float* h0    = ws;                       // N*HID
    float* h1    = h0 + N * HID;             // N*HID
    float* p0    = h1 + N * HID;             // N*HID
    float* p1    = p0 + N * HID;             // N*HID
    float* deg   = p1 + N * HID;             // N
    float* ev    = deg + N;                  // N*MAXD
    int*   nbr   = (int*)(ev + N * MAXD);    // N*MAXD ints
    float* WihT  = (float*)(nbr + N * MAXD); // [64][192]
    float* WhhT  = WihT + 64 * 192;          // [64][192]
    float* WmsgT = WhhT + 64 * 192;          // [64][64]
    float* Wr1T  = WmsgT + 64 * 64;          // [128][64]
    unsigned* bar = (unsigned*)(Wr1T + 128 * 64); // 2 uints

    init_kernel<<<1424, 256, 0, stream>>>(X, W_enc, b_enc, W_msg, b_msg,
                                          W_ih, W_hh, W_r1, A, E,
                                          h0, p0, nbr, ev, deg,
                                          WihT, WhhT, WmsgT, Wr1T, bar);

    steps_kernel<<<SBLK, 256, 0, stream>>>(W_msg, b_msg, nbr, ev, deg,
                                           WihT, WhhT, WmsgT, b_ih, b_hh,
                                           Wr1T, b_r1, W_r2, b_r2, src, tgt,
                                           h0, h1, p0, p1, bar, (float*)d_out);
}

// Round 8
// 41.861 us; speedup vs baseline: 20.1208x; 9.5557x over previous
//
#include <hip/hip_runtime.h>
#include <math.h>

#define N 1024
#define IN_DIM 16
#define HID 64
#define MAXD 64

__device__ __forceinline__ float sigmoidf_(float x) {
    return 1.0f / (1.0f + __expf(-x));
}
// fast tanh via exp; ~1e-6 rel error, far below 1e-2 threshold
__device__ __forceinline__ float ftanh_(float x) {
    float e = __expf(2.0f * x);
    return 1.0f - 2.0f / (e + 1.0f);
}
// round-to-nearest-even fp32 -> bf16 bits
__device__ __forceinline__ unsigned rne16_(float f) {
    unsigned u = __float_as_uint(f);
    return (u + 0x7FFFu + ((u >> 16) & 1u)) >> 16;
}
__device__ __forceinline__ float blo_(unsigned u) {  // low bf16 -> float
    return __uint_as_float(u << 16);
}
__device__ __forceinline__ float bhi_(unsigned u) {  // high bf16 -> float
    return __uint_as_float(u & 0xFFFF0000u);
}

// packed weight word counts
#define WIH_W 6144   // [k2=32][row=192] two bf16 (k=2k2, 2k2+1) per word
#define WHH_W 6144
#define WMSG_W 2048  // [k2=32][j=64]
#define WPACK_W (WIH_W + WHH_W + WMSG_W)  // 14336 u32 = 56 KB

// ---- fused init:
//   blocks [0,256)    : encoder + proj0 (4 nodes/block)
//   blocks [256,1280) : CSR build (1 block/row)
//   blocks [1280,1368): bf16 weight packing + Wr1T transpose
__global__ void init_kernel(const float* __restrict__ X,
                            const float* __restrict__ W_enc,
                            const float* __restrict__ b_enc,
                            const float* __restrict__ W_msg,
                            const float* __restrict__ b_msg,
                            const float* __restrict__ W_ih,
                            const float* __restrict__ W_hh,
                            const float* __restrict__ W_r1,
                            const float* __restrict__ A,
                            const float* __restrict__ E,
                            float* __restrict__ h,
                            float* __restrict__ proj,
                            int* __restrict__ nbr,
                            float* __restrict__ ev,
                            float* __restrict__ deg,
                            unsigned* __restrict__ Wpack,
                            float* __restrict__ Wr1T) {
    int bid = blockIdx.x;
    int tid = threadIdx.x;
    int wave = tid >> 6;
    int lane = tid & 63;

    if (bid < 256) {
        // ---- encoder + proj0 ----
        int u = bid * 4 + wave;
        __shared__ float sh[4][HID];
        float acc = b_enc[lane];
#pragma unroll
        for (int k = 0; k < IN_DIM; ++k)
            acc += X[u * IN_DIM + k] * W_enc[lane * IN_DIM + k];
        float hv = tanhf(acc);
        h[u * HID + lane] = hv;
        sh[wave][lane] = hv;
        __syncthreads();
        float pacc = b_msg[lane];
        const float4* h4 = (const float4*)sh[wave];
#pragma unroll
        for (int k4 = 0; k4 < HID / 4; ++k4) {
            float4 hh = h4[k4];
            const float* w = &W_msg[lane * (HID + 1) + k4 * 4];
            pacc += hh.x * w[0] + hh.y * w[1] + hh.z * w[2] + hh.w * w[3];
        }
        proj[u * HID + lane] = pacc;
    } else if (bid < 1280) {
        // ---- CSR build: one 256-thread block per row u ----
        int u = bid - 256;
        __shared__ unsigned long long balls[16];
        __shared__ int base[16];
        float evr[4];
        bool has[4];
#pragma unroll
        for (int ci = 0; ci < 4; ++ci) {
            int chunk = wave * 4 + ci;
            int v = chunk * 64 + lane;
            float a = A[u * N + v];
            bool hs = (a > 0.0f);
            has[ci] = hs;
            evr[ci] = E[u * N + v];
            unsigned long long b = __ballot(hs);
            if (lane == 0) balls[chunk] = b;
        }
        __syncthreads();
        if (tid == 0) {
            int s = 0;
#pragma unroll
            for (int c = 0; c < 16; ++c) {
                base[c] = s;
                s += __popcll(balls[c]);
            }
            deg[u] = (float)s;
        }
        __syncthreads();
#pragma unroll
        for (int ci = 0; ci < 4; ++ci) {
            int chunk = wave * 4 + ci;
            if (has[ci]) {
                unsigned long long b = balls[chunk];
                int slot = base[chunk] + __popcll(b & ((1ull << lane) - 1ull));
                if (slot < MAXD) {
                    nbr[u * MAXD + slot] = chunk * 64 + lane;
                    ev[u * MAXD + slot] = evr[ci];
                }
            }
        }
    } else {
        // ---- bf16 weight packing: one u32 per thread ----
        int t = (bid - 1280) * 256 + tid;
        if (t < WIH_W) {                       // WihTp[k2*192+row]
            int k2 = t / 192, row = t % 192;
            int k = 2 * k2;
            unsigned lo = rne16_(W_ih[row * 64 + k]);
            unsigned hi = rne16_(W_ih[row * 64 + k + 1]);
            Wpack[t] = lo | (hi << 16);
        } else if (t < WIH_W + WHH_W) {        // WhhTp
            int t0 = t - WIH_W;
            int k2 = t0 / 192, row = t0 % 192;
            int k = 2 * k2;
            unsigned lo = rne16_(W_hh[row * 64 + k]);
            unsigned hi = rne16_(W_hh[row * 64 + k + 1]);
            Wpack[t] = lo | (hi << 16);
        } else if (t < WPACK_W) {              // WmsgTp[k2*64+j]
            int t0 = t - WIH_W - WHH_W;
            int k2 = t0 >> 6, j = t0 & 63;
            int k = 2 * k2;
            unsigned lo = rne16_(W_msg[j * (HID + 1) + k]);
            unsigned hi = rne16_(W_msg[j * (HID + 1) + k + 1]);
            Wpack[t] = lo | (hi << 16);
        } else if (t < WPACK_W + 8192) {       // Wr1T[k*64+j] = W_r1[j*128+k], fp32
            int t0 = t - WPACK_W;
            int j = t0 >> 7, k = t0 & 127;
            Wr1T[k * 64 + j] = W_r1[t0];
        }
    }
}

// ---- fused step: LDS-staged bf16 weights; msg-gather + GRU + proj(h_new) ----
__global__ void step_kernel(const float* __restrict__ proj,      // proj of h_in
                            const float* __restrict__ W_msg,     // only w_e col
                            const float* __restrict__ b_msg,
                            const float* __restrict__ hin,
                            const int* __restrict__ nbr,
                            const float* __restrict__ ev,
                            const float* __restrict__ deg,
                            const unsigned* __restrict__ Wpack,  // 14336 u32
                            const float* __restrict__ b_ih,
                            const float* __restrict__ b_hh,
                            float* __restrict__ hout,
                            float* __restrict__ projout,
                            int do_proj) {
    int tid = threadIdx.x;
    int wave = tid >> 6;     // 4 waves / block, wave = node slot
    int lane = tid & 63;     // lane = hidden index
    int u = blockIdx.x * 4 + wave;

    __shared__ unsigned sw[WPACK_W];   // 56 KB packed weights
    __shared__ float sm[4][2][HID];    // [0]=msgs (later h_new), [1]=h_u

    // stage weights block-wide (uint4 = 16B chunks)
    {
        const uint4* gsrc = (const uint4*)Wpack;
        uint4* dst = (uint4*)sw;
#pragma unroll
        for (int c = 0; c < WPACK_W / 4 / 256; ++c)
            dst[c * 256 + tid] = gsrc[c * 256 + tid];
    }

    // ---- message gather (independent of sw) ----
    float we = W_msg[lane * (HID + 1) + HID];
    float d = deg[u];
    int dn = (int)d;
    float hu = hin[u * HID + lane];
    float sum = 0.0f;
    int i = 0;
    for (; i + 8 <= dn; i += 8) {
        int4 na = *(const int4*)&nbr[u * MAXD + i];
        int4 nb = *(const int4*)&nbr[u * MAXD + i + 4];
        float4 ea = *(const float4*)&ev[u * MAXD + i];
        float4 eb = *(const float4*)&ev[u * MAXD + i + 4];
        float q0 = proj[na.x * HID + lane];
        float q1 = proj[na.y * HID + lane];
        float q2 = proj[na.z * HID + lane];
        float q3 = proj[na.w * HID + lane];
        float q4 = proj[nb.x * HID + lane];
        float q5 = proj[nb.y * HID + lane];
        float q6 = proj[nb.z * HID + lane];
        float q7 = proj[nb.w * HID + lane];
        sum += ftanh_(q0 + ea.x * we) + ftanh_(q1 + ea.y * we)
             + ftanh_(q2 + ea.z * we) + ftanh_(q3 + ea.w * we);
        sum += ftanh_(q4 + eb.x * we) + ftanh_(q5 + eb.y * we)
             + ftanh_(q6 + eb.z * we) + ftanh_(q7 + eb.w * we);
    }
    for (; i + 4 <= dn; i += 4) {
        int4 nb = *(const int4*)&nbr[u * MAXD + i];
        float4 e4 = *(const float4*)&ev[u * MAXD + i];
        float q0 = proj[nb.x * HID + lane];
        float q1 = proj[nb.y * HID + lane];
        float q2 = proj[nb.z * HID + lane];
        float q3 = proj[nb.w * HID + lane];
        sum += ftanh_(q0 + e4.x * we) + ftanh_(q1 + e4.y * we)
             + ftanh_(q2 + e4.z * we) + ftanh_(q3 + e4.w * we);
    }
    for (; i < dn; ++i)
        sum += ftanh_(proj[nbr[u * MAXD + i] * HID + lane]
                      + ev[u * MAXD + i] * we);
    float msg = (dn > 0) ? (sum / d) : 0.0f;

    sm[wave][0][lane] = msg;
    sm[wave][1][lane] = hu;
    __syncthreads();   // sm ready AND sw staged

    // ---- GRU from LDS bf16 weights: lane j = output j ----
    const unsigned* swih = sw;
    const unsigned* swhh = sw + WIH_W;
    float accR  = b_ih[lane]       + b_hh[lane];
    float accZ  = b_ih[64 + lane]  + b_hh[64 + lane];
    float accNi = b_ih[128 + lane];
    float accNh = b_hh[128 + lane];
    const float2* m2 = (const float2*)sm[wave][0];
    const float2* h2 = (const float2*)sm[wave][1];
#pragma unroll
    for (int k2 = 0; k2 < 32; ++k2) {
        float2 mv = m2[k2];
        float2 hv = h2[k2];
        unsigned wiR = swih[k2 * 192 + lane];
        unsigned wiZ = swih[k2 * 192 + 64 + lane];
        unsigned wiN = swih[k2 * 192 + 128 + lane];
        unsigned whR = swhh[k2 * 192 + lane];
        unsigned whZ = swhh[k2 * 192 + 64 + lane];
        unsigned whN = swhh[k2 * 192 + 128 + lane];
        accR  += mv.x * blo_(wiR) + mv.y * bhi_(wiR)
               + hv.x * blo_(whR) + hv.y * bhi_(whR);
        accZ  += mv.x * blo_(wiZ) + mv.y * bhi_(wiZ)
               + hv.x * blo_(whZ) + hv.y * bhi_(whZ);
        accNi += mv.x * blo_(wiN) + mv.y * bhi_(wiN);
        accNh += hv.x * blo_(whN) + hv.y * bhi_(whN);
    }
    float r = sigmoidf_(accR);
    float z = sigmoidf_(accZ);
    float n = ftanh_(accNi + r * accNh);
    float hnew = (1.0f - z) * n + z * hu;
    hout[u * HID + lane] = hnew;

    if (do_proj) {
        __syncthreads();             // all waves done reading sm
        sm[wave][0][lane] = hnew;
        __syncthreads();
        const unsigned* swmsg = sw + WIH_W + WHH_W;
        float pacc = b_msg[lane];
        const float2* n2 = (const float2*)sm[wave][0];
#pragma unroll
        for (int k2 = 0; k2 < 32; ++k2) {
            float2 hh = n2[k2];
            unsigned wm = swmsg[k2 * 64 + lane];
            pacc += hh.x * blo_(wm) + hh.y * bhi_(wm);
        }
        projout[u * HID + lane] = pacc;
    }
}

// ---- readout: scalar sigmoid(MLP(cat(h[s], h[t]))), coalesced W_r1T ----
__global__ void readout_kernel(const float* __restrict__ h,
                               const float* __restrict__ Wr1T,   // [128][64]
                               const float* __restrict__ b_r1,
                               const float* __restrict__ W_r2,
                               const float* __restrict__ b_r2,
                               const int* __restrict__ src,
                               const int* __restrict__ tgt,
                               float* __restrict__ out) {
    int lane = threadIdx.x;  // 64 threads, 1 wave
    int sI = src[0];
    int tI = tgt[0];
    float acc = b_r1[lane];
#pragma unroll 8
    for (int k = 0; k < HID; ++k)
        acc += h[sI * HID + k] * Wr1T[k * 64 + lane];
#pragma unroll 8
    for (int k = 0; k < HID; ++k)
        acc += h[tI * HID + k] * Wr1T[(HID + k) * 64 + lane];
    float hid = fmaxf(acc, 0.0f);
    float p = hid * W_r2[lane];
#pragma unroll
    for (int off = 32; off > 0; off >>= 1)
        p += __shfl_down(p, off);
    if (lane == 0) out[0] = sigmoidf_(p + b_r2[0]);
}

extern "C" void kernel_launch(void* const* d_in, const int* in_sizes, int n_in,
                              void* d_out, int out_size, void* d_ws, size_t ws_size,
                              hipStream_t stream) {
    const float* A     = (const float*)d_in[0];
    const float* E     = (const float*)d_in[1];
    const float* X     = (const float*)d_in[2];
    const float* W_enc = (const float*)d_in[3];
    const float* b_enc = (const float*)d_in[4];
    const float* W_msg = (const float*)d_in[5];
    const float* b_msg = (const float*)d_in[6];
    const float* W_ih  = (const float*)d_in[7];
    const float* W_hh  = (const float*)d_in[8];
    const float* b_ih  = (const float*)d_in[9];
    const float* b_hh  = (const float*)d_in[10];
    const float* W_r1  = (const float*)d_in[11];
    const float* b_r1  = (const float*)d_in[12];
    const float* W_r2  = (const float*)d_in[13];
    const float* b_r2  = (const float*)d_in[14];
    const int*   src   = (const int*)d_in[15];
    const int*   tgt   = (const int*)d_in[16];
    // steps fixed at 3 in the reference.

    // workspace layout
    float* ws    = (float*)d_ws;
    float* h0    = ws;                       // N*HID
    float* h1    = h0 + N * HID;             // N*HID
    float* p0    = h1 + N * HID;             // N*HID
    float* p1    = p0 + N * HID;             // N*HID
    float* deg   = p1 + N * HID;             // N
    float* ev    = deg + N;                  // N*MAXD
    int*   nbr   = (int*)(ev + N * MAXD);    // N*MAXD ints
    unsigned* Wpack = (unsigned*)(nbr + N * MAXD); // 14336 u32 (16B-aligned)
    float* Wr1T  = (float*)(Wpack + WPACK_W);      // [128][64]

    init_kernel<<<1368, 256, 0, stream>>>(X, W_enc, b_enc, W_msg, b_msg,
                                          W_ih, W_hh, W_r1, A, E,
                                          h0, p0, nbr, ev, deg, Wpack, Wr1T);

    float* hc = h0; float* hn = h1;
    float* pc = p0; float* pn = p1;
    for (int s = 0; s < 3; ++s) {
        step_kernel<<<N / 4, 256, 0, stream>>>(pc, W_msg, b_msg, hc, nbr, ev, deg,
                                               Wpack, b_ih, b_hh,
                                               hn, pn, (s < 2) ? 1 : 0);
        float* t = hc; hc = hn; hn = t;
        t = pc; pc = pn; pn = t;
    }

    readout_kernel<<<1, 64, 0, stream>>>(hc, Wr1T, b_r1, W_r2, b_r2, src, tgt,
                                         (float*)d_out);
}